// Round 7
// baseline (128.662 us; speedup 1.0000x reference)
//
#include <hip/hip_runtime.h>
#include <hip/hip_bf16.h>
#include <math.h>

// BatchGATConv: N nodes, B=2 batches, DIN=128, H=4 heads, D=64, E edges.
// Dispatch plan (5 dispatches):
//   D0: memset deg
//   D1: hist (int4, 4 edges/thread) || prep WT          [independent]
//   D2: proj_mfma (pipelined A-loads, double-buffered LDS transpose) || striped scan
//   D3: scatter (int4 loads, atomic cursors)
//   D4: agg (single-pass softmax+gather, unroll 16 for gather MLP)

typedef unsigned short ushort;
typedef __attribute__((ext_vector_type(8))) unsigned short ushort8;
typedef __attribute__((ext_vector_type(8))) short short8v;
typedef __attribute__((ext_vector_type(4))) float f32x4;

constexpr int DIN = 128;
constexpr int B   = 2;
constexpr int H   = 4;
constexpr int D   = 64;
constexpr int HD  = H * D;      // 256
constexpr int BHD = B * HD;     // 512
constexpr int NCOL = 272;       // 256 + 16 (8 el/er cols + 8 zero pad)
constexpr int PREP_ELEMS  = NCOL * DIN;                 // 34816
constexpr int PREP_BLOCKS = (PREP_ELEMS + 255) / 256;   // 136
constexpr int SXS = 72;         // LDS transpose row stride (ushorts)

__device__ __forceinline__ float leaky(float x) { return x >= 0.f ? x : 0.2f * x; }

__device__ __forceinline__ ushort f2bf(float f) {
    return __builtin_bit_cast(ushort, __float2bfloat16(f));
}
__device__ __forceinline__ float bf2f(ushort v) {
    return __uint_as_float(((unsigned int)v) << 16);
}

// ---------------- D1: hist || prep ----------------
__global__ __launch_bounds__(256) void hist_prep_kernel(
    const int* __restrict__ dst, int* __restrict__ deg, int E,
    const float* __restrict__ W, const float* __restrict__ attn_l,
    const float* __restrict__ attn_r, ushort* __restrict__ WT, int histBlocks)
{
    const int t = threadIdx.x;
    const int b = blockIdx.x;
    if (b < histBlocks) {
        int e4 = (b * 256 + t) * 4;
        if (e4 + 3 < E) {
            int4 dd = *(const int4*)(dst + e4);
            atomicAdd(&deg[dd.x], 1); atomicAdd(&deg[dd.y], 1);
            atomicAdd(&deg[dd.z], 1); atomicAdd(&deg[dd.w], 1);
        } else {
            for (int e = e4; e < E; ++e) atomicAdd(&deg[dst[e]], 1);
        }
        return;
    }
    int id = (b - histBlocks) * 256 + t;
    if (id >= PREP_ELEMS) return;
    int c = id >> 7, k = id & 127;
    float v;
    if (c < 256) {
        v = W[k * HD + c];
    } else if (c < 264) {
        int j = c - 256, h = j & 3;
        const float* av = (j < 4 ? attn_l : attn_r) + h * D;
        const float* wp = W + k * HD + h * D;
        float s = 0.f;
        for (int d = 0; d < D; ++d) s = fmaf(wp[d], av[d], s);
        v = s;
    } else {
        v = 0.f;
    }
    WT[c * DIN + k] = f2bf(v);
}

// ---------------- striped coalesced single-block scan ----------------
__device__ void scan_body(const int* __restrict__ deg, int* __restrict__ offs,
                          int* __restrict__ cursor, int n)
{
    __shared__ int wcarry[4];
    const int t = threadIdx.x;
    const int lane = t & 63;
    const int wid = t >> 6;
    int carry = 0;
    const int nstripes = (n + 1023) >> 10;
    for (int s = 0; s < nstripes; ++s) {
        const int base = (s << 10) + t * 4;
        int4 d = make_int4(0, 0, 0, 0);
        if (base + 3 < n) {
            d = *(const int4*)(deg + base);
        } else {
            if (base     < n) d.x = deg[base];
            if (base + 1 < n) d.y = deg[base + 1];
            if (base + 2 < n) d.z = deg[base + 2];
        }
        const int sum4 = (d.x + d.y) + (d.z + d.w);
        int inc = sum4;
#pragma unroll
        for (int o = 1; o < 64; o <<= 1) {
            int v = __shfl_up(inc, o, 64);
            if (lane >= o) inc += v;
        }
        if (lane == 63) wcarry[wid] = inc;
        __syncthreads();
        int wpre = carry;
#pragma unroll
        for (int k = 0; k < 4; ++k) if (k < wid) wpre += wcarry[k];
        const int e0 = wpre + inc - sum4;
        int4 ov;
        ov.x = e0; ov.y = e0 + d.x; ov.z = ov.y + d.y; ov.w = ov.z + d.z;
        if (base + 3 < n) {
            *(int4*)(offs + base) = ov;
            *(int4*)(cursor + base) = ov;
        } else {
            if (base     < n) { offs[base]     = ov.x; cursor[base]     = ov.x; }
            if (base + 1 < n) { offs[base + 1] = ov.y; cursor[base + 1] = ov.y; }
            if (base + 2 < n) { offs[base + 2] = ov.z; cursor[base + 2] = ov.z; }
        }
        carry += (wcarry[0] + wcarry[1]) + (wcarry[2] + wcarry[3]);
        __syncthreads();
    }
    if (t == 0) offs[n] = carry;
}

// ---------------- D2: proj_mfma || scan ----------------
// 256 threads = 4 waves. Block tile: 64 rows x 272 cols, K=128 (R % 64 == 0).
// A-loads software-pipelined one rt ahead; LDS transpose double-buffered.
__global__ __launch_bounds__(256) void proj_scan_kernel(
    const float* __restrict__ feat, const ushort* __restrict__ WT,
    ushort* __restrict__ ftb, float* __restrict__ el, float* __restrict__ er,
    const int* __restrict__ deg, int* __restrict__ offs, int* __restrict__ cursor,
    int N, int nTiles)
{
    if ((int)blockIdx.x >= nTiles) {
        scan_body(deg, offs, cursor, N);
        return;
    }
    __shared__ ushort sxp[4][2][16][SXS];    // wave-private double transpose buffers (18432 B)
    const int t = threadIdx.x;
    const int w = t >> 6;
    const int lane = t & 63;
    const int lr = lane & 15;    // frag row/col index
    const int lk = lane >> 4;    // k-group (k base = lk*8)

    // B fragments (persist): 4 col-tiles x 4 k-steps
    short8v bfrag[4][4];
#pragma unroll
    for (int ct = 0; ct < 4; ++ct) {
        const int col = w * 64 + ct * 16 + lr;
#pragma unroll
        for (int ks = 0; ks < 4; ++ks)
            bfrag[ct][ks] = *(const short8v*)&WT[col * DIN + ks * 32 + lk * 8];
    }
    short8v efrag[4];   // extra tile (cols 256..271)
#pragma unroll
    for (int ks = 0; ks < 4; ++ks)
        efrag[ks] = *(const short8v*)&WT[(256 + lr) * DIN + ks * 32 + lk * 8];

    const int row0 = blockIdx.x * 64;
    const int rrow = lane >> 2;          // readback row 0..15
    const int seg  = lane & 3;           // 16-ushort segment within wave's 64 cols

    // A-fragment loader: 8 fp32x4 loads -> 4 bf16x8 frags for row tile rt
    auto loadA = [&](int rt, short8v aout[4]) {
        const float* fp = feat + (size_t)(row0 + rt * 16 + lr) * DIN + lk * 8;
#pragma unroll
        for (int ks = 0; ks < 4; ++ks) {
            f32x4 x0 = *(const f32x4*)(fp + ks * 32);
            f32x4 x1 = *(const f32x4*)(fp + ks * 32 + 4);
            short8v v;
            v[0] = (short)f2bf(x0[0]); v[1] = (short)f2bf(x0[1]);
            v[2] = (short)f2bf(x0[2]); v[3] = (short)f2bf(x0[3]);
            v[4] = (short)f2bf(x1[0]); v[5] = (short)f2bf(x1[1]);
            v[6] = (short)f2bf(x1[2]); v[7] = (short)f2bf(x1[3]);
            aout[ks] = v;
        }
    };

    short8v aP[4], aN[4];
    loadA(0, aP);

#pragma unroll
    for (int rt = 0; rt < 4; ++rt) {
        if (rt < 3) loadA(rt + 1, aN);   // issue next tile's loads before this tile's MFMAs

        f32x4 acc[4] = {{0.f,0.f,0.f,0.f},{0.f,0.f,0.f,0.f},{0.f,0.f,0.f,0.f},{0.f,0.f,0.f,0.f}};
#pragma unroll
        for (int ct = 0; ct < 4; ++ct)
#pragma unroll
            for (int ks = 0; ks < 4; ++ks)
                acc[ct] = __builtin_amdgcn_mfma_f32_16x16x32_bf16(aP[ks], bfrag[ct][ks], acc[ct], 0, 0, 0);

        // transpose via wave-private LDS (double-buffered; no second barrier needed)
        ushort (* __restrict__ sw)[SXS] = sxp[w][rt & 1];
#pragma unroll
        for (int ct = 0; ct < 4; ++ct)
#pragma unroll
            for (int r = 0; r < 4; ++r)
                sw[lk * 4 + r][ct * 16 + lr] = f2bf(acc[ct][r]);
        __builtin_amdgcn_wave_barrier();   // order reads after writes within the wave
        ushort8 o0 = *(const ushort8*)&sw[rrow][seg * 16];
        ushort8 o1 = *(const ushort8*)&sw[rrow][seg * 16 + 8];
        ushort* gp = ftb + (size_t)(row0 + rt * 16 + rrow) * HD + w * 64 + seg * 16;
        *(ushort8*)gp = o0;
        *(ushort8*)(gp + 8) = o1;

        if (rt == w) {  // extra tile: el/er columns (wave-uniform branch)
            f32x4 acce = {0.f, 0.f, 0.f, 0.f};
#pragma unroll
            for (int ks = 0; ks < 4; ++ks)
                acce = __builtin_amdgcn_mfma_f32_16x16x32_bf16(aP[ks], efrag[ks], acce, 0, 0, 0);
#pragma unroll
            for (int r = 0; r < 4; ++r) {
                const int row = row0 + rt * 16 + lk * 4 + r;
                if (lr < 4)       el[row * 4 + lr]       = acce[r];
                else if (lr < 8)  er[row * 4 + (lr - 4)] = acce[r];
            }
        }

#pragma unroll
        for (int ks = 0; ks < 4; ++ks) aP[ks] = aN[ks];
    }
}

// ---------------- D3: scatter ----------------
__global__ __launch_bounds__(256) void scatter_kernel(
    const int* __restrict__ dst, const int* __restrict__ src,
    int* __restrict__ cursor, int* __restrict__ esrc, int E)
{
    int e4 = (blockIdx.x * 256 + threadIdx.x) * 4;
    if (e4 + 3 < E) {
        int4 dd = *(const int4*)(dst + e4);
        int4 ss = *(const int4*)(src + e4);
        int p0 = atomicAdd(&cursor[dd.x], 1); esrc[p0] = ss.x;
        int p1 = atomicAdd(&cursor[dd.y], 1); esrc[p1] = ss.y;
        int p2 = atomicAdd(&cursor[dd.z], 1); esrc[p2] = ss.z;
        int p3 = atomicAdd(&cursor[dd.w], 1); esrc[p3] = ss.w;
    } else {
        for (int e = e4; e < E; ++e) {
            int pos = atomicAdd(&cursor[dst[e]], 1);
            esrc[pos] = src[e];
        }
    }
}

// ---------------- D4: agg ----------------
// One wave per dst node; lane covers cols 8*lane..8*lane+7 (ushort8 = 16B gather).
// Softmax denominator fused (no max-sub: |logit| <~ 7). Unroll 16 for gather MLP.
__global__ __launch_bounds__(256) void agg_kernel(
    const ushort* __restrict__ ftb, const float* __restrict__ el,
    const float* __restrict__ er, const int* __restrict__ offs,
    const int* __restrict__ esrc, float* __restrict__ out, int N)
{
    const int t = threadIdx.x;
    const int n = blockIdx.x * 4 + (t >> 6);
    if (n >= N) return;
    const int lane = t & 63;
    const int bh = lane >> 3;
    const int beg = offs[n];
    const int end = offs[n + 1];

    const float erd = er[n * 8 + bh];
    const ushort8* __restrict__ ftv = (const ushort8*)ftb;

    float acc[8];
#pragma unroll
    for (int j = 0; j < 8; ++j) acc[j] = 0.f;
    float dsum = 0.f;

    int i = beg;
    for (; i + 15 < end; i += 16) {
        int s[16];
#pragma unroll
        for (int u = 0; u < 16; ++u) s[u] = esrc[i + u];
        float w[16];
#pragma unroll
        for (int u = 0; u < 16; ++u) w[u] = __expf(leaky(el[s[u] * 8 + bh] + erd));
        ushort8 v[16];
#pragma unroll
        for (int u = 0; u < 16; ++u) v[u] = ftv[s[u] * 64 + lane];
#pragma unroll
        for (int u = 0; u < 16; ++u) dsum += w[u];
#pragma unroll
        for (int j = 0; j < 8; ++j) {
            float a = acc[j];
#pragma unroll
            for (int u = 0; u < 16; ++u) a = fmaf(w[u], bf2f(v[u][j]), a);
            acc[j] = a;
        }
    }
    for (; i + 3 < end; i += 4) {
        int s[4];
#pragma unroll
        for (int u = 0; u < 4; ++u) s[u] = esrc[i + u];
        float w[4];
#pragma unroll
        for (int u = 0; u < 4; ++u) w[u] = __expf(leaky(el[s[u] * 8 + bh] + erd));
        ushort8 v[4];
#pragma unroll
        for (int u = 0; u < 4; ++u) v[u] = ftv[s[u] * 64 + lane];
#pragma unroll
        for (int u = 0; u < 4; ++u) dsum += w[u];
#pragma unroll
        for (int j = 0; j < 8; ++j) {
            float a = acc[j];
#pragma unroll
            for (int u = 0; u < 4; ++u) a = fmaf(w[u], bf2f(v[u][j]), a);
            acc[j] = a;
        }
    }
    for (; i < end; ++i) {
        int s0 = esrc[i];
        float w0 = __expf(leaky(el[s0 * 8 + bh] + erd));
        ushort8 v0 = ftv[s0 * 64 + lane];
        dsum += w0;
#pragma unroll
        for (int j = 0; j < 8; ++j) acc[j] = fmaf(w0, bf2f(v0[j]), acc[j]);
    }

    const float sc = (end > beg) ? (1.f / dsum) : 0.f;
    float4 o0, o1;
    o0.x = leaky(acc[0] * sc); o0.y = leaky(acc[1] * sc);
    o0.z = leaky(acc[2] * sc); o0.w = leaky(acc[3] * sc);
    o1.x = leaky(acc[4] * sc); o1.y = leaky(acc[5] * sc);
    o1.z = leaky(acc[6] * sc); o1.w = leaky(acc[7] * sc);
    float* op = out + (size_t)n * BHD + lane * 8;
    *(float4*)op = o0;
    *(float4*)(op + 4) = o1;
}

extern "C" void kernel_launch(void* const* d_in, const int* in_sizes, int n_in,
                              void* d_out, int out_size, void* d_ws, size_t ws_size,
                              hipStream_t stream)
{
    const float* feat   = (const float*)d_in[0];
    const float* W      = (const float*)d_in[1];
    const float* attn_l = (const float*)d_in[2];
    const float* attn_r = (const float*)d_in[3];
    const int*   src    = (const int*)d_in[4];
    const int*   dst    = (const int*)d_in[5];
    float* out = (float*)d_out;

    const int N = in_sizes[0] / (B * DIN);
    const int E = in_sizes[4];
    const int R = N * B;
    const int nTiles = R / 64;                    // 625 for R=40000 (R % 64 == 0)
    const int histBlocks = (E / 4 + 255) / 256;   // int4 edges per thread
    const int edgeBlocks = histBlocks;

    auto align_up = [](size_t x) { return (x + 255) & ~(size_t)255; };
    size_t off = 0;
    char* base = (char*)d_ws;
    ushort* ftb = (ushort*)(base + off); off += align_up((size_t)R * HD * sizeof(ushort));
    float* el   = (float*)(base + off); off += align_up((size_t)R * H * sizeof(float));
    float* er   = (float*)(base + off); off += align_up((size_t)R * H * sizeof(float));
    ushort* WT  = (ushort*)(base + off); off += align_up((size_t)NCOL * DIN * sizeof(ushort));
    int* deg    = (int*)(base + off); off += align_up((size_t)N * sizeof(int));
    int* offs   = (int*)(base + off); off += align_up((size_t)(N + 1) * sizeof(int));
    int* cursor = (int*)(base + off); off += align_up((size_t)N * sizeof(int));
    int* esrc   = (int*)(base + off); off += align_up((size_t)E * sizeof(int));
    (void)ws_size; (void)n_in; (void)out_size;

    hipMemsetAsync(deg, 0, (size_t)N * sizeof(int), stream);

    hist_prep_kernel<<<histBlocks + PREP_BLOCKS, 256, 0, stream>>>(
        dst, deg, E, W, attn_l, attn_r, WT, histBlocks);
    proj_scan_kernel<<<nTiles + 1, 256, 0, stream>>>(
        feat, WT, ftb, el, er, deg, offs, cursor, N, nTiles);
    scatter_kernel<<<edgeBlocks, 256, 0, stream>>>(dst, src, cursor, esrc, E);
    agg_kernel<<<(N + 3) / 4, 256, 0, stream>>>(ftb, el, er, offs, esrc, out, N);
}

// Round 8
// 128.337 us; speedup vs baseline: 1.0025x; 1.0025x over previous
//
#include <hip/hip_runtime.h>
#include <hip/hip_bf16.h>
#include <math.h>

// BatchGATConv: N nodes, B=2 batches, DIN=128, H=4 heads, D=64, E edges.
// Dispatch plan (5 dispatches):
//   D0: memset deg
//   D1: hist (int4, 4 edges/thread) || prep WT          [independent]
//   D2: proj_mfma (pipelined A-loads, double-buffered LDS transpose) || striped scan
//   D3: scatter: CSR fill + per-edge softmax weights (exp moved out of agg)
//   D4: agg (single-pass: linear weight stream + single ftv gather, unroll 8)

typedef unsigned short ushort;
typedef __attribute__((ext_vector_type(8))) unsigned short ushort8;
typedef __attribute__((ext_vector_type(8))) short short8v;
typedef __attribute__((ext_vector_type(4))) float f32x4;

constexpr int DIN = 128;
constexpr int B   = 2;
constexpr int H   = 4;
constexpr int D   = 64;
constexpr int HD  = H * D;      // 256
constexpr int BHD = B * HD;     // 512
constexpr int NCOL = 272;       // 256 + 16 (8 el/er cols + 8 zero pad)
constexpr int PREP_ELEMS  = NCOL * DIN;                 // 34816
constexpr int PREP_BLOCKS = (PREP_ELEMS + 255) / 256;   // 136
constexpr int SXS = 72;         // LDS transpose row stride (ushorts)

__device__ __forceinline__ float leaky(float x) { return x >= 0.f ? x : 0.2f * x; }

__device__ __forceinline__ ushort f2bf(float f) {
    return __builtin_bit_cast(ushort, __float2bfloat16(f));
}
__device__ __forceinline__ float bf2f(ushort v) {
    return __uint_as_float(((unsigned int)v) << 16);
}

// ---------------- D1: hist || prep ----------------
__global__ __launch_bounds__(256) void hist_prep_kernel(
    const int* __restrict__ dst, int* __restrict__ deg, int E,
    const float* __restrict__ W, const float* __restrict__ attn_l,
    const float* __restrict__ attn_r, ushort* __restrict__ WT, int histBlocks)
{
    const int t = threadIdx.x;
    const int b = blockIdx.x;
    if (b < histBlocks) {
        int e4 = (b * 256 + t) * 4;
        if (e4 + 3 < E) {
            int4 dd = *(const int4*)(dst + e4);
            atomicAdd(&deg[dd.x], 1); atomicAdd(&deg[dd.y], 1);
            atomicAdd(&deg[dd.z], 1); atomicAdd(&deg[dd.w], 1);
        } else {
            for (int e = e4; e < E; ++e) atomicAdd(&deg[dst[e]], 1);
        }
        return;
    }
    int id = (b - histBlocks) * 256 + t;
    if (id >= PREP_ELEMS) return;
    int c = id >> 7, k = id & 127;
    float v;
    if (c < 256) {
        v = W[k * HD + c];
    } else if (c < 264) {
        int j = c - 256, h = j & 3;
        const float* av = (j < 4 ? attn_l : attn_r) + h * D;
        const float* wp = W + k * HD + h * D;
        float s = 0.f;
        for (int d = 0; d < D; ++d) s = fmaf(wp[d], av[d], s);
        v = s;
    } else {
        v = 0.f;
    }
    WT[c * DIN + k] = f2bf(v);
}

// ---------------- striped coalesced single-block scan ----------------
__device__ void scan_body(const int* __restrict__ deg, int* __restrict__ offs,
                          int* __restrict__ cursor, int n)
{
    __shared__ int wcarry[4];
    const int t = threadIdx.x;
    const int lane = t & 63;
    const int wid = t >> 6;
    int carry = 0;
    const int nstripes = (n + 1023) >> 10;
    for (int s = 0; s < nstripes; ++s) {
        const int base = (s << 10) + t * 4;
        int4 d = make_int4(0, 0, 0, 0);
        if (base + 3 < n) {
            d = *(const int4*)(deg + base);
        } else {
            if (base     < n) d.x = deg[base];
            if (base + 1 < n) d.y = deg[base + 1];
            if (base + 2 < n) d.z = deg[base + 2];
        }
        const int sum4 = (d.x + d.y) + (d.z + d.w);
        int inc = sum4;
#pragma unroll
        for (int o = 1; o < 64; o <<= 1) {
            int v = __shfl_up(inc, o, 64);
            if (lane >= o) inc += v;
        }
        if (lane == 63) wcarry[wid] = inc;
        __syncthreads();
        int wpre = carry;
#pragma unroll
        for (int k = 0; k < 4; ++k) if (k < wid) wpre += wcarry[k];
        const int e0 = wpre + inc - sum4;
        int4 ov;
        ov.x = e0; ov.y = e0 + d.x; ov.z = ov.y + d.y; ov.w = ov.z + d.z;
        if (base + 3 < n) {
            *(int4*)(offs + base) = ov;
            *(int4*)(cursor + base) = ov;
        } else {
            if (base     < n) { offs[base]     = ov.x; cursor[base]     = ov.x; }
            if (base + 1 < n) { offs[base + 1] = ov.y; cursor[base + 1] = ov.y; }
            if (base + 2 < n) { offs[base + 2] = ov.z; cursor[base + 2] = ov.z; }
        }
        carry += (wcarry[0] + wcarry[1]) + (wcarry[2] + wcarry[3]);
        __syncthreads();
    }
    if (t == 0) offs[n] = carry;
}

// ---------------- D2: proj_mfma || scan ----------------
// 256 threads = 4 waves. Block tile: 64 rows x 272 cols, K=128 (R % 64 == 0).
__global__ __launch_bounds__(256) void proj_scan_kernel(
    const float* __restrict__ feat, const ushort* __restrict__ WT,
    ushort* __restrict__ ftb, float* __restrict__ el, float* __restrict__ er,
    const int* __restrict__ deg, int* __restrict__ offs, int* __restrict__ cursor,
    int N, int nTiles)
{
    if ((int)blockIdx.x >= nTiles) {
        scan_body(deg, offs, cursor, N);
        return;
    }
    __shared__ ushort sxp[4][2][16][SXS];
    const int t = threadIdx.x;
    const int w = t >> 6;
    const int lane = t & 63;
    const int lr = lane & 15;
    const int lk = lane >> 4;

    short8v bfrag[4][4];
#pragma unroll
    for (int ct = 0; ct < 4; ++ct) {
        const int col = w * 64 + ct * 16 + lr;
#pragma unroll
        for (int ks = 0; ks < 4; ++ks)
            bfrag[ct][ks] = *(const short8v*)&WT[col * DIN + ks * 32 + lk * 8];
    }
    short8v efrag[4];
#pragma unroll
    for (int ks = 0; ks < 4; ++ks)
        efrag[ks] = *(const short8v*)&WT[(256 + lr) * DIN + ks * 32 + lk * 8];

    const int row0 = blockIdx.x * 64;
    const int rrow = lane >> 2;
    const int seg  = lane & 3;

    auto loadA = [&](int rt, short8v aout[4]) {
        const float* fp = feat + (size_t)(row0 + rt * 16 + lr) * DIN + lk * 8;
#pragma unroll
        for (int ks = 0; ks < 4; ++ks) {
            f32x4 x0 = *(const f32x4*)(fp + ks * 32);
            f32x4 x1 = *(const f32x4*)(fp + ks * 32 + 4);
            short8v v;
            v[0] = (short)f2bf(x0[0]); v[1] = (short)f2bf(x0[1]);
            v[2] = (short)f2bf(x0[2]); v[3] = (short)f2bf(x0[3]);
            v[4] = (short)f2bf(x1[0]); v[5] = (short)f2bf(x1[1]);
            v[6] = (short)f2bf(x1[2]); v[7] = (short)f2bf(x1[3]);
            aout[ks] = v;
        }
    };

    short8v aP[4], aN[4];
    loadA(0, aP);

#pragma unroll
    for (int rt = 0; rt < 4; ++rt) {
        if (rt < 3) loadA(rt + 1, aN);

        f32x4 acc[4] = {{0.f,0.f,0.f,0.f},{0.f,0.f,0.f,0.f},{0.f,0.f,0.f,0.f},{0.f,0.f,0.f,0.f}};
#pragma unroll
        for (int ct = 0; ct < 4; ++ct)
#pragma unroll
            for (int ks = 0; ks < 4; ++ks)
                acc[ct] = __builtin_amdgcn_mfma_f32_16x16x32_bf16(aP[ks], bfrag[ct][ks], acc[ct], 0, 0, 0);

        ushort (* __restrict__ sw)[SXS] = sxp[w][rt & 1];
#pragma unroll
        for (int ct = 0; ct < 4; ++ct)
#pragma unroll
            for (int r = 0; r < 4; ++r)
                sw[lk * 4 + r][ct * 16 + lr] = f2bf(acc[ct][r]);
        __builtin_amdgcn_wave_barrier();
        ushort8 o0 = *(const ushort8*)&sw[rrow][seg * 16];
        ushort8 o1 = *(const ushort8*)&sw[rrow][seg * 16 + 8];
        ushort* gp = ftb + (size_t)(row0 + rt * 16 + rrow) * HD + w * 64 + seg * 16;
        *(ushort8*)gp = o0;
        *(ushort8*)(gp + 8) = o1;

        if (rt == w) {
            f32x4 acce = {0.f, 0.f, 0.f, 0.f};
#pragma unroll
            for (int ks = 0; ks < 4; ++ks)
                acce = __builtin_amdgcn_mfma_f32_16x16x32_bf16(aP[ks], efrag[ks], acce, 0, 0, 0);
#pragma unroll
            for (int r = 0; r < 4; ++r) {
                const int row = row0 + rt * 16 + lk * 4 + r;
                if (lr < 4)       el[row * 4 + lr]       = acce[r];
                else if (lr < 8)  er[row * 4 + (lr - 4)] = acce[r];
            }
        }

#pragma unroll
        for (int ks = 0; ks < 4; ++ks) aP[ks] = aN[ks];
    }
}

// ---------------- D3: scatter + per-edge weights ----------------
// Fills CSR (esrc) and computes all 8 softmax weights per edge in CSR order.
// el/er are ~1.25 MB each -> gathers are L2-resident; exp leaves agg's hot loop.
__global__ __launch_bounds__(256) void scatter_kernel(
    const int* __restrict__ dst, const int* __restrict__ src,
    const float* __restrict__ el, const float* __restrict__ er,
    int* __restrict__ cursor, int* __restrict__ esrc, float* __restrict__ ew, int E)
{
    auto doEdge = [&](int s, int d) {
        int pos = atomicAdd(&cursor[d], 1);
        esrc[pos] = s;
        const float* elp = el + (size_t)s * 8;
        const float* erp = er + (size_t)d * 8;
        f32x4 a0 = *(const f32x4*)elp;
        f32x4 a1 = *(const f32x4*)(elp + 4);
        f32x4 b0 = *(const f32x4*)erp;
        f32x4 b1 = *(const f32x4*)(erp + 4);
        f32x4 w0, w1;
#pragma unroll
        for (int j = 0; j < 4; ++j) w0[j] = __expf(leaky(a0[j] + b0[j]));
#pragma unroll
        for (int j = 0; j < 4; ++j) w1[j] = __expf(leaky(a1[j] + b1[j]));
        float* wp = ew + (size_t)pos * 8;
        *(f32x4*)wp = w0;
        *(f32x4*)(wp + 4) = w1;
    };
    int e4 = (blockIdx.x * 256 + threadIdx.x) * 4;
    if (e4 + 3 < E) {
        int4 dd = *(const int4*)(dst + e4);
        int4 ss = *(const int4*)(src + e4);
        doEdge(ss.x, dd.x); doEdge(ss.y, dd.y);
        doEdge(ss.z, dd.z); doEdge(ss.w, dd.w);
    } else {
        for (int e = e4; e < E; ++e) doEdge(src[e], dst[e]);
    }
}

// ---------------- D4: agg ----------------
// One wave per dst node; lane covers cols 8*lane..8*lane+7 (ushort8 = 16B gather).
// Weights are a LINEAR fp32 stream (ew, CSR order) -> only ftv gather is random.
__global__ __launch_bounds__(256) void agg_kernel(
    const ushort* __restrict__ ftb, const float* __restrict__ ew,
    const int* __restrict__ offs, const int* __restrict__ esrc,
    float* __restrict__ out, int N)
{
    const int t = threadIdx.x;
    const int n = blockIdx.x * 4 + (t >> 6);
    if (n >= N) return;
    const int lane = t & 63;
    const int bh = lane >> 3;
    const int beg = offs[n];
    const int end = offs[n + 1];

    const ushort8* __restrict__ ftv = (const ushort8*)ftb;

    float acc[8];
#pragma unroll
    for (int j = 0; j < 8; ++j) acc[j] = 0.f;
    float dsum = 0.f;

    int i = beg;
    for (; i + 7 < end; i += 8) {
        int s[8];
#pragma unroll
        for (int u = 0; u < 8; ++u) s[u] = esrc[i + u];
        float w[8];
#pragma unroll
        for (int u = 0; u < 8; ++u) w[u] = ew[(size_t)(i + u) * 8 + bh];
        ushort8 v[8];
#pragma unroll
        for (int u = 0; u < 8; ++u) v[u] = ftv[(size_t)s[u] * 64 + lane];
#pragma unroll
        for (int u = 0; u < 8; ++u) dsum += w[u];
#pragma unroll
        for (int j = 0; j < 8; ++j) {
            float a = acc[j];
#pragma unroll
            for (int u = 0; u < 8; ++u) a = fmaf(w[u], bf2f(v[u][j]), a);
            acc[j] = a;
        }
    }
    for (; i + 1 < end; i += 2) {
        int s0 = esrc[i], s1 = esrc[i + 1];
        float w0 = ew[(size_t)i * 8 + bh];
        float w1 = ew[(size_t)(i + 1) * 8 + bh];
        ushort8 v0 = ftv[(size_t)s0 * 64 + lane];
        ushort8 v1 = ftv[(size_t)s1 * 64 + lane];
        dsum += w0 + w1;
#pragma unroll
        for (int j = 0; j < 8; ++j)
            acc[j] += w0 * bf2f(v0[j]) + w1 * bf2f(v1[j]);
    }
    if (i < end) {
        int s0 = esrc[i];
        float w0 = ew[(size_t)i * 8 + bh];
        ushort8 v0 = ftv[(size_t)s0 * 64 + lane];
        dsum += w0;
#pragma unroll
        for (int j = 0; j < 8; ++j) acc[j] = fmaf(w0, bf2f(v0[j]), acc[j]);
    }

    const float sc = (end > beg) ? (1.f / dsum) : 0.f;
    float4 o0, o1;
    o0.x = leaky(acc[0] * sc); o0.y = leaky(acc[1] * sc);
    o0.z = leaky(acc[2] * sc); o0.w = leaky(acc[3] * sc);
    o1.x = leaky(acc[4] * sc); o1.y = leaky(acc[5] * sc);
    o1.z = leaky(acc[6] * sc); o1.w = leaky(acc[7] * sc);
    float* op = out + (size_t)n * BHD + lane * 8;
    *(float4*)op = o0;
    *(float4*)(op + 4) = o1;
}

extern "C" void kernel_launch(void* const* d_in, const int* in_sizes, int n_in,
                              void* d_out, int out_size, void* d_ws, size_t ws_size,
                              hipStream_t stream)
{
    const float* feat   = (const float*)d_in[0];
    const float* W      = (const float*)d_in[1];
    const float* attn_l = (const float*)d_in[2];
    const float* attn_r = (const float*)d_in[3];
    const int*   src    = (const int*)d_in[4];
    const int*   dst    = (const int*)d_in[5];
    float* out = (float*)d_out;

    const int N = in_sizes[0] / (B * DIN);
    const int E = in_sizes[4];
    const int R = N * B;
    const int nTiles = R / 64;                    // 625 for R=40000 (R % 64 == 0)
    const int histBlocks = (E / 4 + 255) / 256;
    const int edgeBlocks = histBlocks;

    auto align_up = [](size_t x) { return (x + 255) & ~(size_t)255; };
    size_t off = 0;
    char* base = (char*)d_ws;
    ushort* ftb = (ushort*)(base + off); off += align_up((size_t)R * HD * sizeof(ushort));
    float* el   = (float*)(base + off); off += align_up((size_t)R * H * sizeof(float));
    float* er   = (float*)(base + off); off += align_up((size_t)R * H * sizeof(float));
    ushort* WT  = (ushort*)(base + off); off += align_up((size_t)NCOL * DIN * sizeof(ushort));
    int* deg    = (int*)(base + off); off += align_up((size_t)N * sizeof(int));
    int* offs   = (int*)(base + off); off += align_up((size_t)(N + 1) * sizeof(int));
    int* cursor = (int*)(base + off); off += align_up((size_t)N * sizeof(int));
    int* esrc   = (int*)(base + off); off += align_up((size_t)E * sizeof(int));
    float* ew   = (float*)(base + off); off += align_up((size_t)E * 8 * sizeof(float));
    (void)ws_size; (void)n_in; (void)out_size;

    hipMemsetAsync(deg, 0, (size_t)N * sizeof(int), stream);

    hist_prep_kernel<<<histBlocks + PREP_BLOCKS, 256, 0, stream>>>(
        dst, deg, E, W, attn_l, attn_r, WT, histBlocks);
    proj_scan_kernel<<<nTiles + 1, 256, 0, stream>>>(
        feat, WT, ftb, el, er, deg, offs, cursor, N, nTiles);
    scatter_kernel<<<edgeBlocks, 256, 0, stream>>>(dst, src, el, er, cursor, esrc, ew, E);
    agg_kernel<<<(N + 3) / 4, 256, 0, stream>>>(ftb, ew, offs, esrc, out, N);
}